// Round 8
// baseline (410.147 us; speedup 1.0000x reference)
//
#include <hip/hip_runtime.h>
#include <stdint.h>

#define B_  4
#define S_  2048
#define D_  1024
#define H_  16
#define DK_ 64
#define M_  (B_ * S_)   // 8192

typedef __attribute__((ext_vector_type(4))) float  f32x4;
typedef __attribute__((ext_vector_type(8))) __bf16 bf16x8;
typedef __attribute__((ext_vector_type(4))) unsigned short us4;

__device__ __forceinline__ unsigned short cvt_bf16(float f) {
  unsigned u = __float_as_uint(f);
  return (unsigned short)((u + 0x7fffu + ((u >> 16) & 1u)) >> 16);
}

__device__ __forceinline__ f32x4 mfma16(bf16x8 a, bf16x8 b, f32x4 c) {
  return __builtin_amdgcn_mfma_f32_16x16x32_bf16(a, b, c, 0, 0, 0);
}

__device__ __forceinline__ void async16(const void* g, void* l) {
  __builtin_amdgcn_global_load_lds(
      (const __attribute__((address_space(1))) void*)g,
      (__attribute__((address_space(3))) void*)l, 16, 0, 0);
}

// ------------------------------------------------- fused cast (5 tensors -> 1 launch)
#define XN4_ 2097152  // (M_*D_)/4
#define WN4_ 262144   // (D_*D_)/4
__global__ void cast_all(const float* __restrict__ x,
                         const float* __restrict__ wq,
                         const float* __restrict__ wk,
                         const float* __restrict__ wv,
                         const float* __restrict__ wo,
                         unsigned short* __restrict__ dst) {
  const int i = blockIdx.x * blockDim.x + threadIdx.x;
  const float* src;
  int k;
  if (i < XN4_) {
    src = x; k = i;
  } else {
    const int j = i - XN4_;
    const int wsel = j >> 18;          // WN4_ = 2^18
    k = j & (WN4_ - 1);
    src = (wsel == 0) ? wq : (wsel == 1) ? wk : (wsel == 2) ? wv : wo;
  }
  f32x4 v = ((const f32x4*)src)[k];
  us4 o;
  o[0] = cvt_bf16(v[0]); o[1] = cvt_bf16(v[1]);
  o[2] = cvt_bf16(v[2]); o[3] = cvt_bf16(v[3]);
  ((us4*)dst)[i] = o;
}

// ---------------------------------------------------------------- GEMM C = A @ W^T
// OUTMODE 2: f32 [M,N] to Cp.
// OUTMODE 3: fused-QKV routing (cols 0-1023 Q, 1024-2047 K, 2048-3071 V^T).
template <int OUTMODE>
__global__ __launch_bounds__(256) void gemm_bt(
    const unsigned short* __restrict__ A,
    const unsigned short* __restrict__ Bm,
    void* __restrict__ Cp,
    unsigned short* __restrict__ Qo, unsigned short* __restrict__ Ko,
    unsigned short* __restrict__ Vto,
    int Ndim, int Kdim) {
  constexpr int BM = 128, BN = 128, BK = 32;
  __shared__ __align__(16) unsigned short As[BM * BK];
  __shared__ __align__(16) unsigned short Bs[BN * BK];

  const int tid = threadIdx.x;
  const int w = tid >> 6, l = tid & 63;
  const int l16 = l & 15, lg = l >> 4;
  const int wr = w >> 1, wc = w & 1;
  const int rowA0 = blockIdx.y * BM;
  const int rowB0 = blockIdx.x * BN;
  const int l4 = l >> 2;
  const int lk = (l & 3) * 8;

  f32x4 acc[4][4] = {};

  for (int kt = 0; kt < Kdim; kt += BK) {
#pragma unroll
    for (int j = 0; j < 2; ++j) {
      const int chunk = j * 4 + w;
      const int r = chunk * 16 + l4;
      async16(A  + (size_t)(rowA0 + r) * Kdim + kt + lk, &As[chunk * 512]);
      async16(Bm + (size_t)(rowB0 + r) * Kdim + kt + lk, &Bs[chunk * 512]);
    }
    __syncthreads();
    bf16x8 af[4], bfr[4];
#pragma unroll
    for (int m = 0; m < 4; ++m)
      af[m] = *(const bf16x8*)&As[(wr * 64 + m * 16 + l16) * BK + lg * 8];
#pragma unroll
    for (int n = 0; n < 4; ++n)
      bfr[n] = *(const bf16x8*)&Bs[(wc * 64 + n * 16 + l16) * BK + lg * 8];
#pragma unroll
    for (int m = 0; m < 4; ++m)
#pragma unroll
      for (int n = 0; n < 4; ++n)
        acc[m][n] = mfma16(af[m], bfr[n], acc[m][n]);
    __syncthreads();
  }

  const int rb = rowA0 + wr * 64;
  const int cb = rowB0 + wc * 64;
  if constexpr (OUTMODE == 2) {
    float* C = (float*)Cp;
#pragma unroll
    for (int m = 0; m < 4; ++m)
#pragma unroll
      for (int n = 0; n < 4; ++n) {
        const int r0 = rb + m * 16 + lg * 4;
        const int c0 = cb + n * 16 + l16;
#pragma unroll
        for (int j = 0; j < 4; ++j)
          C[(size_t)(r0 + j) * Ndim + c0] = acc[m][n][j];
      }
  } else {  // OUTMODE 3
    const int region = cb >> 10;
    const int cbl = cb & 1023;
    if (region < 2) {
      unsigned short* C = region ? Ko : Qo;
#pragma unroll
      for (int m = 0; m < 4; ++m)
#pragma unroll
        for (int n = 0; n < 4; ++n) {
          const int r0 = rb + m * 16 + lg * 4;
          const int c0 = cbl + n * 16 + l16;
#pragma unroll
          for (int j = 0; j < 4; ++j)
            C[(size_t)(r0 + j) * 1024 + c0] = cvt_bf16(acc[m][n][j]);
        }
    } else {  // V transposed
#pragma unroll
      for (int m = 0; m < 4; ++m)
#pragma unroll
        for (int n = 0; n < 4; ++n) {
          const int r0 = rb + m * 16 + lg * 4;
          const int c0 = cbl + n * 16 + l16;
          us4 v;
#pragma unroll
          for (int j = 0; j < 4; ++j) v[j] = cvt_bf16(acc[m][n][j]);
          *(us4*)&Vto[((size_t)(r0 >> 11) * 1024 + c0) * 2048 + (r0 & 2047)] = v;
        }
    }
  }
}

// ---------------------------------------------------------------- flash attention
// v2 pipeline: double-buffered K/V LDS; tile kv+1 prefetched (global_load_lds)
// BEFORE computing tile kv -> staging latency hidden under compute; ONE
// barrier per iteration (end-of-iter __syncthreads drains vmcnt + separates
// buf reads from next overwrite). A/B passes merged to share K/V fragment
// reads (one ds_read feeds both MFMAs); softmax chains A,B back-to-back for
// VALU ILP. No setprio (barrier-locked structure; m190).

#define KS_ 0.1803368801f  // 0.125 * log2(e)

#define SMX(sc, mr, sr, oa, P, diag, rb, kv0)                                \
  do {                                                                       \
    if (diag) {                                                              \
      _Pragma("unroll") for (int nc_ = 0; nc_ < 4; ++nc_) {                  \
        const int col_ = (kv0) + nc_ * 16 + l16;                             \
        _Pragma("unroll") for (int j_ = 0; j_ < 4; ++j_)                     \
            if (col_ > (rb) + j_) sc[nc_][j_] = -INFINITY;                   \
      }                                                                      \
    }                                                                        \
    _Pragma("unroll") for (int j_ = 0; j_ < 4; ++j_) {                       \
      float t_ = fmaxf(fmaxf(sc[0][j_], sc[1][j_]),                          \
                       fmaxf(sc[2][j_], sc[3][j_]));                         \
      t_ = fmaxf(t_, __shfl_xor(t_, 1));                                     \
      t_ = fmaxf(t_, __shfl_xor(t_, 2));                                     \
      t_ = fmaxf(t_, __shfl_xor(t_, 4));                                     \
      t_ = fmaxf(t_, __shfl_xor(t_, 8));                                     \
      const bool st_ = __all(t_ <= mr[j_]);   /* wave-uniform: no growth */  \
      const float mnew_ = st_ ? mr[j_] : fmaxf(mr[j_], t_);                  \
      float rs_ = 0.f;                                                       \
      _Pragma("unroll") for (int nc_ = 0; nc_ < 4; ++nc_) {                  \
        const float p_ = exp2f((sc[nc_][j_] - mnew_) * KS_);                 \
        rs_ += p_;                                                           \
        P[lg * 4 + j_][nc_ * 16 + l16] = cvt_bf16(p_);                       \
      }                                                                      \
      rs_ += __shfl_xor(rs_, 1);                                             \
      rs_ += __shfl_xor(rs_, 2);                                             \
      rs_ += __shfl_xor(rs_, 4);                                             \
      rs_ += __shfl_xor(rs_, 8);                                             \
      if (st_) {                                                             \
        sr[j_] += rs_;                                                       \
      } else {                                                               \
        const float al_ = exp2f((mr[j_] - mnew_) * KS_);                     \
        sr[j_] = sr[j_] * al_ + rs_;                                         \
        mr[j_] = mnew_;                                                      \
        _Pragma("unroll") for (int d_ = 0; d_ < 4; ++d_) oa[d_][j_] *= al_;  \
      }                                                                      \
    }                                                                        \
  } while (0)

// stage K/V tile kvt into buffer pb (inverse-swizzled global source, rule #21)
#define STAGE(kvt, pb)                                                       \
  do {                                                                       \
    const int kv0_ = (kvt) * 64;                                             \
    _Pragma("unroll") for (int c_ = 0; c_ < 2; ++c_) {                       \
      const int ci_ = c_ * 256 + w * 64;                                     \
      const int i_  = ci_ + l;                                               \
      const int r_  = i_ >> 3;                                               \
      const int cc_ = (i_ & 7) ^ (r_ & 7);                                   \
      async16(K  + qkbase + (size_t)(kv0_ + r_) * D_ + cc_ * 8,              \
              &Ks[pb][ci_ * 8]);                                             \
      async16(Vt + vbase  + (size_t)r_ * S_ + kv0_ + cc_ * 8,                \
              &Vs[pb][ci_ * 8]);                                             \
    }                                                                        \
  } while (0)

__global__ __launch_bounds__(256, 3) void flash_attn(
    const unsigned short* __restrict__ Q,
    const unsigned short* __restrict__ K,
    const unsigned short* __restrict__ Vt,
    unsigned short* __restrict__ O) {
  const int bid  = blockIdx.x;                    // 0..1023
  const int virt = (bid & 7) * 128 + (bid >> 3);  // XCD-grouped remap
  const int bh   = virt >> 4;                     // 0..63 (8 bh per XCD)
  const int x    = virt & 15;                     // 0..15 pair index
  const int b = bh >> 4, h = bh & 15;
  const int tid = threadIdx.x;
  const int w = tid >> 6, l = tid & 63;
  const int l16 = l & 15, lg = l >> 4;

  __shared__ __align__(16) unsigned short Ks[2][64 * 64];  // dbuf, swizzled
  __shared__ __align__(16) unsigned short Vs[2][64 * 64];  // dbuf, swizzled
  __shared__ __align__(16) unsigned short PA[4][16][72];
  __shared__ __align__(16) unsigned short PB[4][16][72];

  const int tA = x, tB = 31 - x;  // tA < tB always

  const size_t qkbase = (size_t)(b * S_) * D_ + h * DK_;
  const size_t vbase  = ((size_t)(b * D_) + h * DK_) * S_;

  const int rA = tA * 64 + w * 16 + l16;
  const int rB = tB * 64 + w * 16 + l16;
  bf16x8 qfA[2], qfB[2];
  qfA[0] = *(const bf16x8*)&Q[qkbase + (size_t)rA * D_ + lg * 8];
  qfA[1] = *(const bf16x8*)&Q[qkbase + (size_t)rA * D_ + 32 + lg * 8];
  qfB[0] = *(const bf16x8*)&Q[qkbase + (size_t)rB * D_ + lg * 8];
  qfB[1] = *(const bf16x8*)&Q[qkbase + (size_t)rB * D_ + 32 + lg * 8];

  float mA[4], sA[4], mB[4], sB[4];
  f32x4 oA[4] = {}, oB[4] = {};
#pragma unroll
  for (int j = 0; j < 4; ++j) {
    mA[j] = mB[j] = -INFINITY;
    sA[j] = sB[j] = 0.f;
  }

  const int rbA = tA * 64 + w * 16 + lg * 4;
  const int rbB = tB * 64 + w * 16 + lg * 4;

  STAGE(0, 0);        // prologue: tile 0 into buf 0
  __syncthreads();    // vmcnt drained by compiler before barrier

  for (int kv = 0; kv <= tB; ++kv) {
    const int p = kv & 1;
    const int kv0 = kv * 64;
    if (kv < tB) STAGE(kv + 1, p ^ 1);  // prefetch next tile (hidden)

    const bool doA = (kv <= tA);  // wave-uniform
    const char* Kp = (const char*)&Ks[p][0];
    const char* Vp = (const char*)&Vs[p][0];

    // QK^T, A and B sharing each K fragment read
    f32x4 scA[4] = {}, scB[4] = {};
#pragma unroll
    for (int nc = 0; nc < 4; ++nc) {
      const int r = nc * 16 + l16;
#pragma unroll
      for (int ks = 0; ks < 2; ++ks) {
        const int byte = (r * 128 + ks * 64 + lg * 16) ^ ((r & 7) << 4);
        bf16x8 kf = *(const bf16x8*)(Kp + byte);
        if (doA) scA[nc] = mfma16(qfA[ks], kf, scA[nc]);
        scB[nc] = mfma16(qfB[ks], kf, scB[nc]);
      }
    }

    if (doA) SMX(scA, mA, sA, oA, PA[w], kv == tA, rbA, kv0);
    SMX(scB, mB, sB, oB, PB[w], kv == tB, rbB, kv0);

    __asm__ volatile("s_waitcnt lgkmcnt(0)" ::: "memory");  // P visible (own wave)
    bf16x8 paA0, paA1, paB0, paB1;
    if (doA) {
      paA0 = *(const bf16x8*)&PA[w][l16][lg * 8];
      paA1 = *(const bf16x8*)&PA[w][l16][32 + lg * 8];
    }
    paB0 = *(const bf16x8*)&PB[w][l16][lg * 8];
    paB1 = *(const bf16x8*)&PB[w][l16][32 + lg * 8];

    // PV, A and B sharing each V fragment read
#pragma unroll
    for (int d = 0; d < 4; ++d) {
      const int r = d * 16 + l16;
#pragma unroll
      for (int ks = 0; ks < 2; ++ks) {
        const int byte = (r * 128 + ks * 64 + lg * 16) ^ ((r & 7) << 4);
        bf16x8 vf = *(const bf16x8*)(Vp + byte);
        if (doA) oA[d] = mfma16(ks ? paA1 : paA0, vf, oA[d]);
        oB[d] = mfma16(ks ? paB1 : paB0, vf, oB[d]);
      }
    }
    __syncthreads();  // drains prefetch vmcnt; separates buf reuse
  }

#pragma unroll
  for (int j = 0; j < 4; ++j) {
    const float iA = __builtin_amdgcn_rcpf(sA[j]);
    const float iB = __builtin_amdgcn_rcpf(sB[j]);
#pragma unroll
    for (int d = 0; d < 4; ++d) {
      O[((size_t)(b * S_) + rbA + j) * D_ + h * DK_ + d * 16 + l16] =
          cvt_bf16(oA[d][j] * iA);
      O[((size_t)(b * S_) + rbB + j) * D_ + h * DK_ + d * 16 + l16] =
          cvt_bf16(oB[d][j] * iB);
    }
  }
}

// ---------------------------------------------------------------- launch
extern "C" void kernel_launch(void* const* d_in, const int* in_sizes, int n_in,
                              void* d_out, int out_size, void* d_ws,
                              size_t ws_size, hipStream_t stream) {
  const float* x  = (const float*)d_in[0];
  const float* Wq = (const float*)d_in[1];
  const float* Wk = (const float*)d_in[2];
  const float* Wv = (const float*)d_in[3];
  const float* Wo = (const float*)d_in[4];

  const size_t XN = (size_t)M_ * D_;   // 8388608
  const size_t WN = (size_t)D_ * D_;   // 1048576
  unsigned short* xb  = (unsigned short*)d_ws;
  unsigned short* Wqb = xb + XN;       // Wq|Wk|Wv contiguous = fused [3072,1024]
  unsigned short* Wob = Wqb + 3 * WN;
  unsigned short* Qb  = Wob + WN;
  unsigned short* Kb  = Qb + XN;
  unsigned short* Vtb = Kb + XN;
  unsigned short* Ob  = Vtb + XN;

  cast_all<<<(XN4_ + 4 * WN4_) / 256, 256, 0, stream>>>(x, Wq, Wk, Wv, Wo, xb);

  gemm_bt<3><<<dim3(24, 64), 256, 0, stream>>>(xb, Wqb, nullptr, Qb, Kb, Vtb,
                                               3072, D_);

  flash_attn<<<dim3(1024), 256, 0, stream>>>(Qb, Kb, Vtb, Ob);

  gemm_bt<2><<<dim3(8, 64), 256, 0, stream>>>(Ob, Wob, d_out, nullptr, nullptr,
                                              nullptr, D_, D_);
}

// Round 9
// 304.935 us; speedup vs baseline: 1.3450x; 1.3450x over previous
//
#include <hip/hip_runtime.h>
#include <stdint.h>

#define B_  4
#define S_  2048
#define D_  1024
#define H_  16
#define DK_ 64
#define M_  (B_ * S_)   // 8192

typedef __attribute__((ext_vector_type(4))) float  f32x4;
typedef __attribute__((ext_vector_type(8))) __bf16 bf16x8;
typedef __attribute__((ext_vector_type(4))) unsigned short us4;

__device__ __forceinline__ unsigned short cvt_bf16(float f) {
  unsigned u = __float_as_uint(f);
  return (unsigned short)((u + 0x7fffu + ((u >> 16) & 1u)) >> 16);
}

__device__ __forceinline__ f32x4 mfma16(bf16x8 a, bf16x8 b, f32x4 c) {
  return __builtin_amdgcn_mfma_f32_16x16x32_bf16(a, b, c, 0, 0, 0);
}

__device__ __forceinline__ void async16(const void* g, void* l) {
  __builtin_amdgcn_global_load_lds(
      (const __attribute__((address_space(1))) void*)g,
      (__attribute__((address_space(3))) void*)l, 16, 0, 0);
}

// ------------------------------------------------- fused cast (5 tensors -> 1 launch)
#define XN4_ 2097152  // (M_*D_)/4
#define WN4_ 262144   // (D_*D_)/4
__global__ void cast_all(const float* __restrict__ x,
                         const float* __restrict__ wq,
                         const float* __restrict__ wk,
                         const float* __restrict__ wv,
                         const float* __restrict__ wo,
                         unsigned short* __restrict__ dst) {
  const int i = blockIdx.x * blockDim.x + threadIdx.x;
  const float* src;
  int k;
  if (i < XN4_) {
    src = x; k = i;
  } else {
    const int j = i - XN4_;
    const int wsel = j >> 18;          // WN4_ = 2^18
    k = j & (WN4_ - 1);
    src = (wsel == 0) ? wq : (wsel == 1) ? wk : (wsel == 2) ? wv : wo;
  }
  f32x4 v = ((const f32x4*)src)[k];
  us4 o;
  o[0] = cvt_bf16(v[0]); o[1] = cvt_bf16(v[1]);
  o[2] = cvt_bf16(v[2]); o[3] = cvt_bf16(v[3]);
  ((us4*)dst)[i] = o;
}

// ---------------------------------------------------------------- GEMM C = A @ W^T
// BK=64: half the K-iterations of the BK=32 version -> half the
// vmcnt-drain+barrier pairs (the m97 structure's ~20% stall). 128-B LDS rows
// would be a 16-way bank conflict, so tiles are XOR-swizzled both sides
// (rule #21): inverse-swizzled global source feeding linear global_load_lds,
// matching XOR on the ds_read byte -> 2-way (free).
// OUTMODE 2: f32 [M,N] to Cp.
// OUTMODE 3: fused-QKV routing (cols 0-1023 Q, 1024-2047 K, 2048-3071 V^T).
template <int OUTMODE>
__global__ __launch_bounds__(256) void gemm_bt(
    const unsigned short* __restrict__ A,
    const unsigned short* __restrict__ Bm,
    void* __restrict__ Cp,
    unsigned short* __restrict__ Qo, unsigned short* __restrict__ Ko,
    unsigned short* __restrict__ Vto,
    int Ndim, int Kdim) {
  constexpr int BM = 128, BN = 128, BK = 64;
  __shared__ __align__(16) unsigned short As[BM * BK];
  __shared__ __align__(16) unsigned short Bs[BN * BK];

  const int tid = threadIdx.x;
  const int w = tid >> 6, l = tid & 63;
  const int l16 = l & 15, lg = l >> 4;
  const int wr = w >> 1, wc = w & 1;
  const int rowA0 = blockIdx.y * BM;
  const int rowB0 = blockIdx.x * BN;

  f32x4 acc[4][4] = {};

  for (int kt = 0; kt < Kdim; kt += BK) {
#pragma unroll
    for (int j = 0; j < 4; ++j) {
      const int ci = j * 256 + w * 64;   // wave-uniform chunk-group base
      const int i  = ci + l;             // 16B chunk 0..1023
      const int r  = i >> 3;             // tile row 0..127
      const int cc = (i & 7) ^ (r & 7);  // inverse-swizzled 16B col chunk
      async16(A  + (size_t)(rowA0 + r) * Kdim + kt + cc * 8, &As[ci * 8]);
      async16(Bm + (size_t)(rowB0 + r) * Kdim + kt + cc * 8, &Bs[ci * 8]);
    }
    __syncthreads();  // vmcnt drained before barrier -> staging complete
#pragma unroll
    for (int hf = 0; hf < 2; ++hf) {
      bf16x8 af[4], bfr[4];
#pragma unroll
      for (int m = 0; m < 4; ++m) {
        const int r = wr * 64 + m * 16 + l16;
        const int byte = (r * 128) + ((lg * 16 + hf * 64) ^ ((r & 7) << 4));
        af[m] = *(const bf16x8*)((const char*)As + byte);
      }
#pragma unroll
      for (int n = 0; n < 4; ++n) {
        const int r = wc * 64 + n * 16 + l16;
        const int byte = (r * 128) + ((lg * 16 + hf * 64) ^ ((r & 7) << 4));
        bfr[n] = *(const bf16x8*)((const char*)Bs + byte);
      }
#pragma unroll
      for (int m = 0; m < 4; ++m)
#pragma unroll
        for (int n = 0; n < 4; ++n)
          acc[m][n] = mfma16(af[m], bfr[n], acc[m][n]);
    }
    __syncthreads();
  }

  const int rb = rowA0 + wr * 64;
  const int cb = rowB0 + wc * 64;
  if constexpr (OUTMODE == 2) {
    float* C = (float*)Cp;
#pragma unroll
    for (int m = 0; m < 4; ++m)
#pragma unroll
      for (int n = 0; n < 4; ++n) {
        const int r0 = rb + m * 16 + lg * 4;
        const int c0 = cb + n * 16 + l16;
#pragma unroll
        for (int j = 0; j < 4; ++j)
          C[(size_t)(r0 + j) * Ndim + c0] = acc[m][n][j];
      }
  } else {  // OUTMODE 3
    const int region = cb >> 10;
    const int cbl = cb & 1023;
    if (region < 2) {
      unsigned short* C = region ? Ko : Qo;
#pragma unroll
      for (int m = 0; m < 4; ++m)
#pragma unroll
        for (int n = 0; n < 4; ++n) {
          const int r0 = rb + m * 16 + lg * 4;
          const int c0 = cbl + n * 16 + l16;
#pragma unroll
          for (int j = 0; j < 4; ++j)
            C[(size_t)(r0 + j) * 1024 + c0] = cvt_bf16(acc[m][n][j]);
        }
    } else {  // V transposed
#pragma unroll
      for (int m = 0; m < 4; ++m)
#pragma unroll
        for (int n = 0; n < 4; ++n) {
          const int r0 = rb + m * 16 + lg * 4;
          const int c0 = cbl + n * 16 + l16;
          us4 v;
#pragma unroll
          for (int j = 0; j < 4; ++j) v[j] = cvt_bf16(acc[m][n][j]);
          *(us4*)&Vto[((size_t)(r0 >> 11) * 1024 + c0) * 2048 + (r0 & 2047)] = v;
        }
    }
  }
}

// ---------------------------------------------------------------- flash attention
// Round-5 structure (best measured: 134 us, VGPR 64, no spill): one block =
// (b,h) x paired q-tiles {x, 31-x}; A/B passes SERIALIZED per KV tile (caps
// live regs so (256,4) fits 128 VGPRs); K/V staged once per tile in
// XOR-swizzled single-buffer LDS; XCD-grouped blocks. R6's VALU diet and R8's
// dbuf+merge both regressed (setprio/defer-max neutral-negative; merge
// spilled) -> reverted.

#define SMX(sc, mr, sr, oa, P, diag, rb, kv0)                                \
  do {                                                                       \
    _Pragma("unroll") for (int nc_ = 0; nc_ < 4; ++nc_)                      \
        _Pragma("unroll") for (int j_ = 0; j_ < 4; ++j_)                     \
            sc[nc_][j_] *= 0.125f;                                           \
    if (diag) {                                                              \
      _Pragma("unroll") for (int nc_ = 0; nc_ < 4; ++nc_) {                  \
        const int col_ = (kv0) + nc_ * 16 + l16;                             \
        _Pragma("unroll") for (int j_ = 0; j_ < 4; ++j_)                     \
            if (col_ > (rb) + j_) sc[nc_][j_] = -INFINITY;                   \
      }                                                                      \
    }                                                                        \
    _Pragma("unroll") for (int j_ = 0; j_ < 4; ++j_) {                       \
      float t_ = fmaxf(fmaxf(sc[0][j_], sc[1][j_]),                          \
                       fmaxf(sc[2][j_], sc[3][j_]));                         \
      t_ = fmaxf(t_, __shfl_xor(t_, 1));                                     \
      t_ = fmaxf(t_, __shfl_xor(t_, 2));                                     \
      t_ = fmaxf(t_, __shfl_xor(t_, 4));                                     \
      t_ = fmaxf(t_, __shfl_xor(t_, 8));                                     \
      const float mnew_ = fmaxf(mr[j_], t_);                                 \
      float rs_ = 0.f;                                                       \
      _Pragma("unroll") for (int nc_ = 0; nc_ < 4; ++nc_) {                  \
        const float p_ = __expf(sc[nc_][j_] - mnew_);                        \
        rs_ += p_;                                                           \
        P[lg * 4 + j_][nc_ * 16 + l16] = cvt_bf16(p_);                       \
      }                                                                      \
      rs_ += __shfl_xor(rs_, 1);                                             \
      rs_ += __shfl_xor(rs_, 2);                                             \
      rs_ += __shfl_xor(rs_, 4);                                             \
      rs_ += __shfl_xor(rs_, 8);                                             \
      const float al_ = __expf(mr[j_] - mnew_);                              \
      sr[j_] = sr[j_] * al_ + rs_;                                           \
      mr[j_] = mnew_;                                                        \
      _Pragma("unroll") for (int d_ = 0; d_ < 4; ++d_) oa[d_][j_] *= al_;    \
    }                                                                        \
  } while (0)

__global__ __launch_bounds__(256, 4) void flash_attn(
    const unsigned short* __restrict__ Q,
    const unsigned short* __restrict__ K,
    const unsigned short* __restrict__ Vt,
    unsigned short* __restrict__ O) {
  const int bid  = blockIdx.x;                    // 0..1023
  const int virt = (bid & 7) * 128 + (bid >> 3);  // XCD-grouped remap
  const int bh   = virt >> 4;                     // 0..63 (8 bh per XCD)
  const int x    = virt & 15;                     // 0..15 pair index
  const int b = bh >> 4, h = bh & 15;
  const int tid = threadIdx.x;
  const int w = tid >> 6, l = tid & 63;
  const int l16 = l & 15, lg = l >> 4;

  __shared__ __align__(16) unsigned short Ks[64 * 64];  // [s][dk] swizzled
  __shared__ __align__(16) unsigned short Vs[64 * 64];  // [dk][s] swizzled
  __shared__ __align__(16) unsigned short PA[4][16][72];
  __shared__ __align__(16) unsigned short PB[4][16][72];

  const int tA = x, tB = 31 - x;  // tA < tB always

  const size_t qkbase = (size_t)(b * S_) * D_ + h * DK_;
  const size_t vbase  = ((size_t)(b * D_) + h * DK_) * S_;

  const int rA = tA * 64 + w * 16 + l16;
  const int rB = tB * 64 + w * 16 + l16;
  bf16x8 qfA[2], qfB[2];
  qfA[0] = *(const bf16x8*)&Q[qkbase + (size_t)rA * D_ + lg * 8];
  qfA[1] = *(const bf16x8*)&Q[qkbase + (size_t)rA * D_ + 32 + lg * 8];
  qfB[0] = *(const bf16x8*)&Q[qkbase + (size_t)rB * D_ + lg * 8];
  qfB[1] = *(const bf16x8*)&Q[qkbase + (size_t)rB * D_ + 32 + lg * 8];

  float mA[4], sA[4], mB[4], sB[4];
  f32x4 oA[4] = {}, oB[4] = {};
#pragma unroll
  for (int j = 0; j < 4; ++j) {
    mA[j] = mB[j] = -INFINITY;
    sA[j] = sB[j] = 0.f;
  }

  const int rbA = tA * 64 + w * 16 + lg * 4;  // +j = global q row (set A)
  const int rbB = tB * 64 + w * 16 + lg * 4;

  for (int kv = 0; kv <= tB; ++kv) {
    const int kv0 = kv * 64;
    if (kv) __syncthreads();  // previous tile fully consumed before overwrite
#pragma unroll
    for (int c = 0; c < 2; ++c) {
      const int ci = c * 256 + w * 64;  // wave-uniform chunk base
      const int i  = ci + l;            // per-lane chunk 0..511
      const int r  = i >> 3;            // tile row
      const int cc = (i & 7) ^ (r & 7); // swizzled 16B column
      async16(K  + qkbase + (size_t)(kv0 + r) * D_ + cc * 8, &Ks[ci * 8]);
      async16(Vt + vbase  + (size_t)r * S_ + kv0 + cc * 8,   &Vs[ci * 8]);
    }
    __syncthreads();  // staging complete

    // ---- A pass (wave-uniform predicate) ----
    if (kv <= tA) {
      f32x4 sc[4] = {};
#pragma unroll
      for (int nc = 0; nc < 4; ++nc) {
        const int r = nc * 16 + l16;
#pragma unroll
        for (int ks = 0; ks < 2; ++ks) {
          const int byte = (r * 128 + ks * 64 + lg * 16) ^ ((r & 7) << 4);
          bf16x8 kf = *(const bf16x8*)((const char*)Ks + byte);
          sc[nc] = mfma16(qfA[ks], kf, sc[nc]);
        }
      }
      SMX(sc, mA, sA, oA, PA[w], kv == tA, rbA, kv0);
      __asm__ volatile("s_waitcnt lgkmcnt(0)" ::: "memory");
      bf16x8 pa0 = *(const bf16x8*)&PA[w][l16][lg * 8];
      bf16x8 pa1 = *(const bf16x8*)&PA[w][l16][32 + lg * 8];
#pragma unroll
      for (int d = 0; d < 4; ++d) {
        const int r = d * 16 + l16;
#pragma unroll
        for (int ks = 0; ks < 2; ++ks) {
          const int byte = (r * 128 + ks * 64 + lg * 16) ^ ((r & 7) << 4);
          bf16x8 vf = *(const bf16x8*)((const char*)Vs + byte);
          oA[d] = mfma16(ks ? pa1 : pa0, vf, oA[d]);
        }
      }
    }

    // ---- B pass (always active) ----
    {
      f32x4 sc[4] = {};
#pragma unroll
      for (int nc = 0; nc < 4; ++nc) {
        const int r = nc * 16 + l16;
#pragma unroll
        for (int ks = 0; ks < 2; ++ks) {
          const int byte = (r * 128 + ks * 64 + lg * 16) ^ ((r & 7) << 4);
          bf16x8 kf = *(const bf16x8*)((const char*)Ks + byte);
          sc[nc] = mfma16(qfB[ks], kf, sc[nc]);
        }
      }
      SMX(sc, mB, sB, oB, PB[w], kv == tB, rbB, kv0);
      __asm__ volatile("s_waitcnt lgkmcnt(0)" ::: "memory");
      bf16x8 pb0 = *(const bf16x8*)&PB[w][l16][lg * 8];
      bf16x8 pb1 = *(const bf16x8*)&PB[w][l16][32 + lg * 8];
#pragma unroll
      for (int d = 0; d < 4; ++d) {
        const int r = d * 16 + l16;
#pragma unroll
        for (int ks = 0; ks < 2; ++ks) {
          const int byte = (r * 128 + ks * 64 + lg * 16) ^ ((r & 7) << 4);
          bf16x8 vf = *(const bf16x8*)((const char*)Vs + byte);
          oB[d] = mfma16(ks ? pb1 : pb0, vf, oB[d]);
        }
      }
    }
  }

#pragma unroll
  for (int d = 0; d < 4; ++d)
#pragma unroll
    for (int j = 0; j < 4; ++j) {
      O[((size_t)(b * S_) + rbA + j) * D_ + h * DK_ + d * 16 + l16] =
          cvt_bf16(oA[d][j] / sA[j]);
      O[((size_t)(b * S_) + rbB + j) * D_ + h * DK_ + d * 16 + l16] =
          cvt_bf16(oB[d][j] / sB[j]);
    }
}

// ---------------------------------------------------------------- launch
extern "C" void kernel_launch(void* const* d_in, const int* in_sizes, int n_in,
                              void* d_out, int out_size, void* d_ws,
                              size_t ws_size, hipStream_t stream) {
  const float* x  = (const float*)d_in[0];
  const float* Wq = (const float*)d_in[1];
  const float* Wk = (const float*)d_in[2];
  const float* Wv = (const float*)d_in[3];
  const float* Wo = (const float*)d_in[4];

  const size_t XN = (size_t)M_ * D_;   // 8388608
  const size_t WN = (size_t)D_ * D_;   // 1048576
  unsigned short* xb  = (unsigned short*)d_ws;
  unsigned short* Wqb = xb + XN;       // Wq|Wk|Wv contiguous = fused [3072,1024]
  unsigned short* Wob = Wqb + 3 * WN;
  unsigned short* Qb  = Wob + WN;
  unsigned short* Kb  = Qb + XN;
  unsigned short* Vtb = Kb + XN;
  unsigned short* Ob  = Vtb + XN;

  cast_all<<<(XN4_ + 4 * WN4_) / 256, 256, 0, stream>>>(x, Wq, Wk, Wv, Wo, xb);

  gemm_bt<3><<<dim3(24, 64), 256, 0, stream>>>(xb, Wqb, nullptr, Qb, Kb, Vtb,
                                               3072, D_);

  flash_attn<<<dim3(1024), 256, 0, stream>>>(Qb, Kb, Vtb, Ob);

  gemm_bt<2><<<dim3(8, 64), 256, 0, stream>>>(Ob, Wob, d_out, nullptr, nullptr,
                                              nullptr, D_, D_);
}